// Round 9
// baseline (245.251 us; speedup 1.0000x reference)
//
#include <hip/hip_runtime.h>
#include <stdint.h>

// ---- types ----
typedef __bf16 bf16x8 __attribute__((ext_vector_type(8)));
typedef __bf16 bf16x4 __attribute__((ext_vector_type(4)));
typedef short  s16x4  __attribute__((ext_vector_type(4)));
typedef float  f32x4  __attribute__((ext_vector_type(4)));
typedef unsigned int u32x4 __attribute__((ext_vector_type(4)));
typedef unsigned short u16;

__device__ __forceinline__ u16 f2bf(float f) {
    union { float f; unsigned u; } v; v.f = f;
    unsigned r = v.u + 0x7fffu + ((v.u >> 16) & 1u);
    return (u16)(r >> 16);
}

// packed 2x f32 -> bf16 (RNE); [15:0]=a, [31:16]=b
__device__ __forceinline__ unsigned pk_bf16(float a, float b) {
#if __has_builtin(__builtin_amdgcn_cvt_pk_bf16_f32)
    typedef __bf16 bf16x2_t __attribute__((ext_vector_type(2)));
    bf16x2_t r = __builtin_amdgcn_cvt_pk_bf16_f32(a, b);
    return __builtin_bit_cast(unsigned, r);
#else
    return (unsigned)f2bf(a) | ((unsigned)f2bf(b) << 16);
#endif
}

__device__ __forceinline__ bf16x8 ld_frag(const u16* p) {
    u32x4 u = *(const u32x4*)p;
    return __builtin_bit_cast(bf16x8, u);
}

// K=16 bf16 MFMA (C/D row layout == A/B k layout: in-register P transform)
__device__ __forceinline__ f32x4 mfma16(bf16x4 a, bf16x4 b, f32x4 c) {
#if __has_builtin(__builtin_amdgcn_mfma_f32_16x16x16_bf16)
    return __builtin_amdgcn_mfma_f32_16x16x16_bf16(a, b, c, 0, 0, 0);
#else
    return __builtin_amdgcn_mfma_f32_16x16x16bf16_1k(
        __builtin_bit_cast(s16x4, a), __builtin_bit_cast(s16x4, b), c, 0, 0, 0);
#endif
}

// async global->LDS, 16B per lane; LDS dest = wave-uniform base + lane*16
__device__ __forceinline__ void gload16(const u16* g, u16* l) {
    __builtin_amdgcn_global_load_lds(
        (__attribute__((address_space(1))) void*)g,
        (__attribute__((address_space(3))) void*)l,
        16, 0, 0);
}

#define ATT_CSC 0.18033688011112042f  // (1/sqrt(64)) * log2(e)

// ---- fused fp32 -> bf16 convert for all 4 arrays (float4-granular) ----
__global__ __launch_bounds__(256) void cvt_all(
    const float* __restrict__ x, const float* __restrict__ wg,
    const float* __restrict__ wqkv, const float* __restrict__ wproj,
    u16* __restrict__ xo, u16* __restrict__ wgo,
    u16* __restrict__ wqkvo, u16* __restrict__ wprojo)
{
    int i = blockIdx.x * 256 + threadIdx.x;   // grid covers exactly 2359296
    const float4* in; uint2* out; int off;
    if (i < 1048576)      { in = (const float4*)x;     out = (uint2*)xo;     off = i; }
    else if (i < 1310720) { in = (const float4*)wg;    out = (uint2*)wgo;    off = i - 1048576; }
    else if (i < 2097152) { in = (const float4*)wqkv;  out = (uint2*)wqkvo;  off = i - 1310720; }
    else                  { in = (const float4*)wproj; out = (uint2*)wprojo; off = i - 2097152; }
    float4 v = in[off];
    uint2 o; o.x = pk_bf16(v.x, v.y); o.y = pk_bf16(v.z, v.w);
    out[off] = o;
}

// ---- 128x128xBK32 bf16 MFMA GEMM (QKV), XOR-swizzled LDS ----
__global__ __launch_bounds__(256) void gemm_bt(
    const u16* __restrict__ A,      // [4096,1024]
    const u16* __restrict__ W,      // [3072,1024]
    const float* __restrict__ bias,
    u16* __restrict__ qo, u16* __restrict__ ko, u16* __restrict__ vTo)
{
    __shared__ alignas(16) u16 As[128 * 32];
    __shared__ alignas(16) u16 Bs[128 * 32];
    const int tid  = threadIdx.x;
    const int wave = tid >> 6, lane = tid & 63;
    const int lquad = lane >> 4, lcol = lane & 15;
    const int wr = (wave >> 1) * 64, wc = (wave & 1) * 64;
    const int rowb = blockIdx.x * 128, colb = blockIdx.y * 128;
    const int swc = (((lane & 3) ^ ((lane >> 2) & 3)) * 8);  // swizzled source chunk
    const int rsw = (lquad ^ (lcol & 3)) * 8;                // swizzled read chunk

    const u16* src  = (wave & 2) ? W : A;
    const int  rbase = (wave & 2) ? colb : rowb;
    u16* dst = ((wave & 2) ? Bs : As) + (wave & 1) * 64 * 32;
    const u16* gsrc = src + (size_t)(rbase + (wave & 1) * 64 + (lane >> 2)) * 1024 + swc;

    f32x4 zero4 = {0.f, 0.f, 0.f, 0.f};
    f32x4 acc[4][4];
#pragma unroll
    for (int i = 0; i < 4; i++)
#pragma unroll
        for (int j = 0; j < 4; j++) acc[i][j] = zero4;

    for (int k0 = 0; k0 < 1024; k0 += 32) {
        __syncthreads();
#pragma unroll
        for (int i = 0; i < 4; i++)
            gload16(gsrc + (size_t)(i * 16) * 1024 + k0, dst + i * 16 * 32);
        __syncthreads();
        bf16x8 af[4], bfr[4];
#pragma unroll
        for (int t = 0; t < 4; t++) af[t]  = ld_frag(As + (wr + t * 16 + lcol) * 32 + rsw);
#pragma unroll
        for (int t = 0; t < 4; t++) bfr[t] = ld_frag(Bs + (wc + t * 16 + lcol) * 32 + rsw);
#pragma unroll
        for (int i = 0; i < 4; i++)
#pragma unroll
            for (int j = 0; j < 4; j++)
                acc[i][j] = __builtin_amdgcn_mfma_f32_16x16x32_bf16(af[i], bfr[j], acc[i][j], 0, 0, 0);
    }

#pragma unroll
    for (int i = 0; i < 4; i++) {
#pragma unroll
        for (int j = 0; j < 4; j++) {
            int gcol = colb + wc + j * 16 + lcol;
            float bsv = bias[gcol];
            int grow0 = rowb + wr + i * 16 + lquad * 4;
            int three = gcol >> 10, rem = gcol & 1023;
            int h = rem >> 6, d = rem & 63;
            int b = grow0 >> 11, nn = grow0 & 2047;
            int bh = b * 16 + h;
            if (three == 2) {
                ushort4 o;
                o.x = f2bf(acc[i][j][0] + bsv);
                o.y = f2bf(acc[i][j][1] + bsv);
                o.z = f2bf(acc[i][j][2] + bsv);
                o.w = f2bf(acc[i][j][3] + bsv);
                *(ushort4*)(vTo + ((size_t)bh * 64 + d) * 2048 + nn) = o;
            } else if (three == 0) {
#pragma unroll
                for (int r = 0; r < 4; r++)
                    qo[((size_t)bh * 2048 + nn + r) * 64 + d] = f2bf((acc[i][j][r] + bsv) * ATT_CSC);
            } else {
#pragma unroll
                for (int r = 0; r < 4; r++)
                    ko[((size_t)bh * 2048 + nn + r) * 64 + d] = f2bf(acc[i][j][r] + bsv);
            }
        }
    }
}

// ---- 64x128xBK32 GEMM (gauge mode0 / proj mode2), grid (64, 8) = 512 blocks ----
__global__ __launch_bounds__(256) void gemm64(
    int mode,
    const u16* __restrict__ A,
    const u16* __restrict__ W,
    const float* __restrict__ bias,
    const float* __restrict__ xres,
    const float* __restrict__ theta,
    u16* __restrict__ out_bf,
    float* __restrict__ out_f)
{
    __shared__ alignas(16) u16 As[64 * 32];
    __shared__ alignas(16) u16 Bs[128 * 32];
    const int tid  = threadIdx.x;
    const int wave = tid >> 6, lane = tid & 63;
    const int lquad = lane >> 4, lcol = lane & 15;
    const int wr = (wave & 1) * 32, wc = (wave >> 1) * 64;
    const int rowb = blockIdx.x * 64, colb = blockIdx.y * 128;
    const int swc = (((lane & 3) ^ ((lane >> 2) & 3)) * 8);
    const int rsw = (lquad ^ (lcol & 3)) * 8;

    const u16* gp[3]; u16* lp[3];
#pragma unroll
    for (int t = 0; t < 3; t++) {
        int id = wave + t * 4;
        if (id < 4) {
            gp[t] = A + (size_t)(rowb + id * 16 + (lane >> 2)) * 1024 + swc;
            lp[t] = As + id * 512;
        } else {
            int g = id - 4;
            gp[t] = W + (size_t)(colb + g * 16 + (lane >> 2)) * 1024 + swc;
            lp[t] = Bs + g * 512;
        }
    }

    f32x4 zero4 = {0.f, 0.f, 0.f, 0.f};
    f32x4 acc[2][4];
#pragma unroll
    for (int i = 0; i < 2; i++)
#pragma unroll
        for (int j = 0; j < 4; j++) acc[i][j] = zero4;

    for (int k0 = 0; k0 < 1024; k0 += 32) {
        __syncthreads();
#pragma unroll
        for (int t = 0; t < 3; t++)
            gload16(gp[t] + k0, lp[t]);
        __syncthreads();
        bf16x8 af[2], bfr[4];
#pragma unroll
        for (int t = 0; t < 2; t++) af[t]  = ld_frag(As + (wr + t * 16 + lcol) * 32 + rsw);
#pragma unroll
        for (int t = 0; t < 4; t++) bfr[t] = ld_frag(Bs + (wc + t * 16 + lcol) * 32 + rsw);
#pragma unroll
        for (int i = 0; i < 2; i++)
#pragma unroll
            for (int j = 0; j < 4; j++)
                acc[i][j] = __builtin_amdgcn_mfma_f32_16x16x32_bf16(af[i], bfr[j], acc[i][j], 0, 0, 0);
    }

#pragma unroll
    for (int i = 0; i < 2; i++) {
#pragma unroll
        for (int j = 0; j < 4; j++) {
            int gcol = colb + wc + j * 16 + lcol;
            float bsv = bias[gcol];
            int grow0 = rowb + wr + i * 16 + lquad * 4;
            if (mode == 0) {
#pragma unroll
                for (int r = 0; r < 4; r++) {
                    size_t idx = (size_t)(grow0 + r) * 1024 + gcol;
                    float val = acc[i][j][r] + bsv;
                    out_bf[idx] = f2bf(xres[idx] + 0.1f * (val * theta[gcol]));
                }
            } else {
#pragma unroll
                for (int r = 0; r < 4; r++)
                    out_f[(size_t)(grow0 + r) * 1024 + gcol] = acc[i][j][r] + bsv;
            }
        }
    }
}

// ---- flash attention: j-tile 128, in-register P via K=16 PV MFMA ----
// S^T = K Q'^T (q pre-scaled, K=32 MFMA); P = exp2(S^T) stays in regs;
// O^T += V^T P^T via 16x16x16 MFMA (C/D row layout == B k layout).
// block: 4 waves x 32 q-rows = 128 q-rows; grid (16, 32)
__global__ __launch_bounds__(256) void attn_kernel(
    const u16* __restrict__ q,   // [B*H, N, D] (pre-scaled by csc)
    const u16* __restrict__ k,   // [B*H, N, D]
    const u16* __restrict__ vT,  // [B*H, D, N]
    u16* __restrict__ attnout)   // [B, N, H*D]
{
    __shared__ alignas(16) u16 Ks[2 * 2 * 64 * 32];   // [jh][db][j][32] 16KB
    __shared__ alignas(16) u16 Vs[2 * 2 * 64 * 32];   // [jh][jb][d][32] 16KB

    const int tid  = threadIdx.x;
    const int wave = tid >> 6, lane = tid & 63;
    const int lquad = lane >> 4, lcol = lane & 15;
    const int bh   = blockIdx.y;
    const int row0 = blockIdx.x * 128 + wave * 32;
    const int rsw  = (lquad ^ (lcol & 3)) * 8;

    // Q as B-operand: n=lcol (q-row), k=d ; two q-halves of 16
    bf16x8 qf[2][2];
#pragma unroll
    for (int qh = 0; qh < 2; qh++)
#pragma unroll
        for (int db = 0; db < 2; db++)
            qf[qh][db] = ld_frag(q + ((size_t)bh * 2048 + row0 + qh * 16 + lcol) * 64 + db * 32 + lquad * 8);

    f32x4 zero4 = {0.f, 0.f, 0.f, 0.f};
    f32x4 lacc[2] = {zero4, zero4};
    f32x4 oacc[2][4];
#pragma unroll
    for (int qh = 0; qh < 2; qh++)
#pragma unroll
        for (int dt = 0; dt < 4; dt++) oacc[qh][dt] = zero4;

    // staging: wave 0,1 -> K halves (d-split); wave 2,3 -> V^T halves (j-split)
    const int sb = wave & 1;
    const int srow = lane >> 2;
    const int swc  = (((lane & 3) ^ (srow & 3)) * 8);
    const u16* gK = k  + ((size_t)bh * 2048 + srow) * 64 + sb * 32 + swc;
    const u16* gV = vT + ((size_t)bh * 64 + srow) * 2048 + sb * 32 + swc;
    u16* ldst = ((wave & 2) ? Vs : Ks) + sb * 64 * 32;

    // V b64 read swizzle pieces: chunk = ((jt&1)*2 + (lquad>>1)) ^ (lcol&3), +8B if lquad odd
    const int vq_hi = lquad >> 1, vq_lo = (lquad & 1) * 4;   // u16 units

    for (int j0 = 0; j0 < 2048; j0 += 128) {
        __syncthreads();
        if ((wave & 2) == 0) {
#pragma unroll
            for (int jh = 0; jh < 2; jh++)
#pragma unroll
                for (int i = 0; i < 4; i++)
                    gload16(gK + (size_t)(j0 + jh * 64 + i * 16) * 64, ldst + jh * 4096 + i * 16 * 32);
        } else {
#pragma unroll
            for (int jh = 0; jh < 2; jh++)
#pragma unroll
                for (int i = 0; i < 4; i++)
                    gload16(gV + (size_t)(i * 16) * 2048 + j0 + jh * 64, ldst + jh * 4096 + i * 16 * 32);
        }
        __syncthreads();

#pragma unroll
        for (int jh = 0; jh < 2; jh++) {
            const u16* Ksb = Ks + jh * 4096;
            const u16* Vsb = Vs + jh * 4096;

            // S^T = K Q'^T : rows j (4 frags), col q = lcol; kf reused across q-halves
            f32x4 sacc[2][4];
#pragma unroll
            for (int qh = 0; qh < 2; qh++)
#pragma unroll
                for (int jt = 0; jt < 4; jt++) sacc[qh][jt] = zero4;
#pragma unroll
            for (int jt = 0; jt < 4; jt++)
#pragma unroll
                for (int db = 0; db < 2; db++) {
                    bf16x8 kf = ld_frag(Ksb + db * 64 * 32 + (jt * 16 + lcol) * 32 + rsw);
#pragma unroll
                    for (int qh = 0; qh < 2; qh++)
                        sacc[qh][jt] = __builtin_amdgcn_mfma_f32_16x16x32_bf16(kf, qf[qh][db], sacc[qh][jt], 0, 0, 0);
                }

            // per 16-j chunk: p = exp2(s) in regs -> PV B-operand; V^T b64 frags
#pragma unroll
            for (int jt = 0; jt < 4; jt++) {
                bf16x4 pf[2];
#pragma unroll
                for (int qh = 0; qh < 2; qh++) {
                    f32x4 pe;
                    pe[0] = __builtin_amdgcn_exp2f(sacc[qh][jt][0]);
                    pe[1] = __builtin_amdgcn_exp2f(sacc[qh][jt][1]);
                    pe[2] = __builtin_amdgcn_exp2f(sacc[qh][jt][2]);
                    pe[3] = __builtin_amdgcn_exp2f(sacc[qh][jt][3]);
                    lacc[qh] += pe;
                    uint2 u;
                    u.x = pk_bf16(pe[0], pe[1]);
                    u.y = pk_bf16(pe[2], pe[3]);
                    pf[qh] = __builtin_bit_cast(bf16x4, u);
                }
                const int jb = jt >> 1;
                const int ch = (((jt & 1) * 2 + vq_hi) ^ (lcol & 3)) * 8 + vq_lo;
#pragma unroll
                for (int dt = 0; dt < 4; dt++) {
                    const u16* vp = Vsb + jb * 2048 + (dt * 16 + lcol) * 32 + ch;
                    bf16x4 vf = __builtin_bit_cast(bf16x4, *(const uint2*)vp);
                    oacc[0][dt] = mfma16(vf, pf[0], oacc[0][dt]);
                    oacc[1][dt] = mfma16(vf, pf[1], oacc[1][dt]);
                }
            }
        }
    }

    // epilogue: O^T[d][q]/l -> attnout[b, n=q, h*64+d]
    const int b = bh >> 4, h = bh & 15;
#pragma unroll
    for (int qh = 0; qh < 2; qh++) {
        float l = (lacc[qh][0] + lacc[qh][1]) + (lacc[qh][2] + lacc[qh][3]);
        l += __shfl_xor(l, 16, 64);
        l += __shfl_xor(l, 32, 64);
        float inv = 1.0f / l;
        const int n = row0 + qh * 16 + lcol;
        size_t base = ((size_t)b * 2048 + n) * 1024 + h * 64;
#pragma unroll
        for (int dt = 0; dt < 4; dt++) {
            uint2 o;
            o.x = pk_bf16(oacc[qh][dt][0] * inv, oacc[qh][dt][1] * inv);
            o.y = pk_bf16(oacc[qh][dt][2] * inv, oacc[qh][dt][3] * inv);
            *(uint2*)(attnout + base + dt * 16 + lquad * 4) = o;
        }
    }
}

extern "C" void kernel_launch(void* const* d_in, const int* in_sizes, int n_in,
                              void* d_out, int out_size, void* d_ws, size_t ws_size,
                              hipStream_t stream) {
    const float* x     = (const float*)d_in[0];
    const float* theta = (const float*)d_in[1];
    const float* Wg    = (const float*)d_in[2];
    const float* bg    = (const float*)d_in[3];
    const float* Wqkv  = (const float*)d_in[4];
    const float* bqkv  = (const float*)d_in[5];
    const float* Wproj = (const float*)d_in[6];
    const float* bproj = (const float*)d_in[7];
    float* out = (float*)d_out;

    unsigned char* ws = (unsigned char*)d_ws;
    const size_t MB = 1ull << 20;
    u16* x_bf     = (u16*)(ws + 0);
    u16* Wg_bf    = (u16*)(ws + 8 * MB);
    u16* Wqkv_bf  = (u16*)(ws + 10 * MB);
    u16* Wproj_bf = (u16*)(ws + 16 * MB);
    u16* xg_bf    = (u16*)(ws + 18 * MB);
    u16* q_bf     = (u16*)(ws + 26 * MB);
    u16* k_bf     = (u16*)(ws + 34 * MB);
    u16* vT_bf    = (u16*)(ws + 42 * MB);
    u16* ao_bf    = (u16*)(ws + 50 * MB);

    dim3 blk(256);
    cvt_all<<<9216, blk, 0, stream>>>(x, Wg, Wqkv, Wproj,
                                      x_bf, Wg_bf, Wqkv_bf, Wproj_bf);

    gemm64<<<dim3(64, 8), blk, 0, stream>>>(0, x_bf, Wg_bf, bg,
                                            x, theta, xg_bf, nullptr);
    gemm_bt<<<dim3(32, 24), blk, 0, stream>>>(xg_bf, Wqkv_bf, bqkv,
                                              q_bf, k_bf, vT_bf);
    attn_kernel<<<dim3(16, 32), blk, 0, stream>>>(q_bf, k_bf, vT_bf, ao_bf);
    gemm64<<<dim3(64, 8), blk, 0, stream>>>(2, ao_bf, Wproj_bf, bproj,
                                            nullptr, nullptr, nullptr, out);
}